// Round 7
// baseline (95.665 us; speedup 1.0000x reference)
//
#include <hip/hip_runtime.h>

#define N_SAMPLES 128
#define EPS 1e-10f

typedef float f4 __attribute__((ext_vector_type(4)));

// One 64-lane wave handles TWO rays (a "pair"): lanes 0-31 -> even ray, 32-63 -> odd ray.
// rgb is loaded with perfectly contiguous per-instruction bursts (3 x float4 per lane at
// wave-flat indices lane, lane+64, lane+128 -> each instruction = 1024 B / 16 full lines),
// staged in LDS, then re-read in the per-ray permuted pattern. Alpha is contiguous as-is.
// weights[s] = alpha[s] * prod_{j<s}(1 - alpha[j] + EPS)
__global__ __launch_bounds__(256) void VolumeRenderer_14336600834233_kernel(
    const f4* __restrict__ alpha4,
    const f4* __restrict__ rgb4,
    float* __restrict__ out,
    int n_pairs)
{
    __shared__ f4 lds[4][192];                    // 3 KiB per wave, 12 KiB per block

    const int wid  = threadIdx.x >> 6;            // wave id in block
    const int lane = threadIdx.x & 63;
    const int g    = lane >> 5;                   // which ray of the pair
    const int l    = lane & 31;                   // lane within 32-lane group
    const int pair = blockIdx.x * 4 + wid;
    const bool active = pair < n_pairs;

    f4 av;
    if (active) {
        // alpha: 2 rays = 64 float4, flat index pair*64 + lane (fully contiguous)
        av = alpha4[(size_t)pair * 64 + lane];

        // rgb: 2 rays = 192 float4; three contiguous 1024 B bursts
        const size_t rbase = (size_t)pair * 192;
        const f4 r0 = rgb4[rbase + lane];
        const f4 r1 = rgb4[rbase + lane + 64];
        const f4 r2 = rgb4[rbase + lane + 128];
        lds[wid][lane]       = r0;
        lds[wid][lane + 64]  = r1;
        lds[wid][lane + 128] = r2;
    }
    __syncthreads();
    if (!active) return;

    // ---- weights from alpha (same as R3) ----
    const float f0 = 1.0f - av.x + EPS;
    const float f1 = 1.0f - av.y + EPS;
    const float f2 = 1.0f - av.z + EPS;
    const float f3 = 1.0f - av.w + EPS;
    const float p  = (f0 * f1) * (f2 * f3);

    float incl = p;
    #pragma unroll
    for (int off = 1; off < 32; off <<= 1) {
        float v = __shfl_up(incl, off, 64);
        incl = (l >= off) ? incl * v : incl;
    }
    float excl = __shfl_up(incl, 1, 64);
    if (l == 0) excl = 1.0f;

    const float w0 = av.x * excl;
    const float t1 = excl * f0;
    const float w1 = av.y * t1;
    const float t2 = t1 * f1;
    const float w2 = av.z * t2;
    const float w3 = av.w * (t2 * f2);

    // ---- rgb from LDS, per-ray permuted pattern: float4 indices g*96 + 3l + {0,1,2} ----
    const int li = g * 96 + 3 * l;
    const f4 x0 = lds[wid][li + 0];   // [r0,g0,b0,r1]
    const f4 x1 = lds[wid][li + 1];   // [g1,b1,r2,g2]
    const f4 x2 = lds[wid][li + 2];   // [b2,r3,g3,b3]

    float cr = fmaf(w0, x0.x, fmaf(w1, x0.w, fmaf(w2, x1.z, w3 * x2.y)));
    float cg = fmaf(w0, x0.y, fmaf(w1, x1.x, fmaf(w2, x1.w, w3 * x2.z)));
    float cb = fmaf(w0, x0.z, fmaf(w1, x1.y, fmaf(w2, x2.x, w3 * x2.w)));

    // ---- sum-reduce within each 32-lane group (5 shfl_xor steps) ----
    #pragma unroll
    for (int off = 16; off; off >>= 1) {
        cr += __shfl_xor(cr, off, 64);
        cg += __shfl_xor(cg, off, 64);
        cb += __shfl_xor(cb, off, 64);
    }

    if (l == 0) {
        const int ray = pair * 2 + g;
        float* o = out + (size_t)ray * 3;
        o[0] = cr;
        o[1] = cg;
        o[2] = cb;
    }
}

extern "C" void kernel_launch(void* const* d_in, const int* in_sizes, int n_in,
                              void* d_out, int out_size, void* d_ws, size_t ws_size,
                              hipStream_t stream) {
    const f4* alpha4 = (const f4*)d_in[0];
    const f4* rgb4   = (const f4*)d_in[1];
    float* out = (float*)d_out;

    const int n_rays  = in_sizes[0] / N_SAMPLES;   // 262144
    const int n_pairs = n_rays / 2;                // 131072

    const int block = 256;                         // 4 waves -> 4 pairs (8 rays) per block
    const int grid  = (n_pairs + 3) / 4;           // 32768 (exact for this shape)

    VolumeRenderer_14336600834233_kernel<<<grid, block, 0, stream>>>(
        alpha4, rgb4, out, n_pairs);
}